// Round 1
// baseline (272.032 us; speedup 1.0000x reference)
//
#include <hip/hip_runtime.h>
#include <hip/hip_bf16.h>

typedef __bf16 bf16x8 __attribute__((ext_vector_type(8)));
typedef short short8 __attribute__((ext_vector_type(8)));
typedef float f32x4 __attribute__((ext_vector_type(4)));

union BF8 { short8 s; bf16x8 b; };

#define N_NODES 4096
#define F_IN 512
#define F_OUT 64
#define NHEAD 8
#define HID 512
#define NCLS 10
#define GAT_ALPHA 0.2f
#define NEGINF -9e15f

__device__ inline unsigned short f2bf(float f) {
  unsigned u = __builtin_bit_cast(unsigned, f);
  unsigned r = (u + 0x7FFFu + ((u >> 16) & 1u)) >> 16;
  return (unsigned short)r;
}
__device__ inline float bf2f(unsigned short h) {
  unsigned u = ((unsigned)h) << 16;
  return __builtin_bit_cast(float, u);
}

// ---------------- GEMM1: Whcat[n][h*64+o] = x @ W, also WhbT bf16 ----------
__global__ __launch_bounds__(256) void gemm1_kernel(
    const float* __restrict__ x, const float* __restrict__ W,
    float* __restrict__ Whcat, unsigned short* __restrict__ WhbT) {
  __shared__ short As[64 * 40];   // [row][k] bf16, stride 40 (pad)
  __shared__ short Bs[64 * 40];   // [o][k]   bf16, stride 40 (pad)
  const int bx = blockIdx.x;      // 64-row tile
  const int h  = blockIdx.y;      // head
  const int t  = threadIdx.x;
  const int w  = t >> 6, l = t & 63;
  const int lr = l & 15, ls = l >> 4;
  f32x4 acc[4] = {};
  for (int k0 = 0; k0 < F_IN; k0 += 32) {
    {   // stage A: 64 rows x 32 k
      int r = t >> 2, c0 = (t & 3) * 8;
      const float* src = x + (bx * 64 + r) * F_IN + k0 + c0;
      float4 v0 = *(const float4*)src;
      float4 v1 = *(const float4*)(src + 4);
      short8 sv;
      sv[0]=f2bf(v0.x); sv[1]=f2bf(v0.y); sv[2]=f2bf(v0.z); sv[3]=f2bf(v0.w);
      sv[4]=f2bf(v1.x); sv[5]=f2bf(v1.y); sv[6]=f2bf(v1.z); sv[7]=f2bf(v1.w);
      *(short8*)&As[r * 40 + c0] = sv;
    }
    {   // stage B: W[h][k0+kk][o] -> Bs[o][kk] (transposed)
      int kk = t >> 3, o0 = (t & 7) * 8;
      const float* src = W + ((h * F_IN) + k0 + kk) * F_OUT + o0;
      float4 v0 = *(const float4*)src;
      float4 v1 = *(const float4*)(src + 4);
      float vv[8] = {v0.x, v0.y, v0.z, v0.w, v1.x, v1.y, v1.z, v1.w};
      #pragma unroll
      for (int i = 0; i < 8; ++i) Bs[(o0 + i) * 40 + kk] = f2bf(vv[i]);
    }
    __syncthreads();
    BF8 a; a.s = *(short8*)&As[(w * 16 + lr) * 40 + ls * 8];
    #pragma unroll
    for (int fc = 0; fc < 4; ++fc) {
      BF8 b; b.s = *(short8*)&Bs[(fc * 16 + lr) * 40 + ls * 8];
      acc[fc] = __builtin_amdgcn_mfma_f32_16x16x32_bf16(a.b, b.b, acc[fc], 0, 0, 0);
    }
    __syncthreads();
  }
  #pragma unroll
  for (int fc = 0; fc < 4; ++fc)
    #pragma unroll
    for (int j = 0; j < 4; ++j) {
      int row = bx * 64 + w * 16 + ls * 4 + j;   // C/D: row=(l>>4)*4+j
      int col = fc * 16 + lr;                    // C/D: col=l&15
      float v = acc[fc][j];
      Whcat[row * HID + h * F_OUT + col] = v;
      WhbT[(h * F_OUT + col) * N_NODES + row] = f2bf(v);
    }
}

// ---------------- f1/f2 ----------------------------------------------------
__global__ __launch_bounds__(512) void f12_kernel(
    const float* __restrict__ Whcat, const float* __restrict__ a1,
    const float* __restrict__ a2, float* __restrict__ f1, float* __restrict__ f2) {
  int n = blockIdx.x;
  int w = threadIdx.x >> 6, l = threadIdx.x & 63;
  float v = Whcat[n * HID + w * F_OUT + l];
  float s1 = v * a1[w * F_OUT + l];
  float s2 = v * a2[w * F_OUT + l];
  #pragma unroll
  for (int off = 32; off > 0; off >>= 1) {
    s1 += __shfl_xor(s1, off, 64);
    s2 += __shfl_xor(s2, off, 64);
  }
  if (l == 0) { f1[w * N_NODES + n] = s1; f2[w * N_NODES + n] = s2; }
}

// ---------------- ATT1: flash-style per-head attention + ELU ---------------
__global__ __launch_bounds__(512) void att1_kernel(
    const int* __restrict__ adj, const float* __restrict__ f1,
    const float* __restrict__ f2, const unsigned short* __restrict__ WhbT,
    unsigned short* __restrict__ hcat) {
  __shared__ short p_lds[8][16][72];   // per-wave p tile, padded
  const int nb = blockIdx.x * 16;
  const int t = threadIdx.x;
  const int h = t >> 6;                // wave = head
  const int l = t & 63;
  const int r = l & 15, s = l >> 4;
  const float f1v = f1[h * N_NODES + nb + r];
  float M = NEGINF, S = 0.f;
  f32x4 acc[4] = {};
  for (int tb = 0; tb < N_NODES; tb += 64) {
    // phase A: logits for row r (lane-owned), m = tb + s*16 + [0,16)
    float ln[16];
    const int*   arow = adj + (nb + r) * N_NODES + tb + s * 16;
    const float* f2p  = f2 + h * N_NODES + tb + s * 16;
    #pragma unroll
    for (int q = 0; q < 4; ++q) {
      int4   a4 = *(const int4*)(arow + q * 4);
      float4 fq = *(const float4*)(f2p + q * 4);
      float v, lv;
      v = f1v + fq.x; lv = v > 0.f ? v : GAT_ALPHA * v; ln[q*4+0] = a4.x ? lv : NEGINF;
      v = f1v + fq.y; lv = v > 0.f ? v : GAT_ALPHA * v; ln[q*4+1] = a4.y ? lv : NEGINF;
      v = f1v + fq.z; lv = v > 0.f ? v : GAT_ALPHA * v; ln[q*4+2] = a4.z ? lv : NEGINF;
      v = f1v + fq.w; lv = v > 0.f ? v : GAT_ALPHA * v; ln[q*4+3] = a4.w ? lv : NEGINF;
    }
    float tmax = ln[0];
    #pragma unroll
    for (int i = 1; i < 16; ++i) tmax = fmaxf(tmax, ln[i]);
    tmax = fmaxf(tmax, __shfl_xor(tmax, 16, 64));
    tmax = fmaxf(tmax, __shfl_xor(tmax, 32, 64));
    float newM = fmaxf(M, tmax);
    float sc = __expf(M - newM);
    M = newM;
    float p[16]; float ps = 0.f;
    #pragma unroll
    for (int i = 0; i < 16; ++i) { p[i] = __expf(ln[i] - newM); ps += p[i]; }
    ps += __shfl_xor(ps, 16, 64);
    ps += __shfl_xor(ps, 32, 64);
    S = S * sc + ps;
    short8 pv0, pv1;
    #pragma unroll
    for (int i = 0; i < 8; ++i) { pv0[i] = (short)f2bf(p[i]); pv1[i] = (short)f2bf(p[i + 8]); }
    *(short8*)&p_lds[h][r][s * 16]     = pv0;
    *(short8*)&p_lds[h][r][s * 16 + 8] = pv1;
    // rescale acc by per-row factor (C/D row = s*4+j lives in lane s*4+j's bookkeeping)
    #pragma unroll
    for (int j = 0; j < 4; ++j) {
      float scj = __shfl(sc, s * 4 + j, 64);
      #pragma unroll
      for (int fc = 0; fc < 4; ++fc) acc[fc][j] *= scj;
    }
    // phase B: p(16x64) @ Wh(64x64) via MFMA
    #pragma unroll
    for (int kf = 0; kf < 2; ++kf) {
      BF8 a; a.s = *(short8*)&p_lds[h][r][kf * 32 + s * 8];
      #pragma unroll
      for (int fc = 0; fc < 4; ++fc) {
        BF8 b;
        b.s = *(const short8*)&WhbT[(h * F_OUT + fc * 16 + r) * N_NODES + tb + kf * 32 + s * 8];
        acc[fc] = __builtin_amdgcn_mfma_f32_16x16x32_bf16(a.b, b.b, acc[fc], 0, 0, 0);
      }
    }
  }
  // epilogue: divide by S, ELU, store bf16 hcat
  float rS[4];
  #pragma unroll
  for (int j = 0; j < 4; ++j) rS[j] = 1.0f / __shfl(S, s * 4 + j, 64);
  #pragma unroll
  for (int fc = 0; fc < 4; ++fc)
    #pragma unroll
    for (int j = 0; j < 4; ++j) {
      float v = acc[fc][j] * rS[j];
      float e = v > 0.f ? v : (__expf(v) - 1.0f);
      hcat[(nb + s * 4 + j) * HID + h * F_OUT + fc * 16 + r] = f2bf(e);
    }
}

// ---------------- GEMM2: Wh2 = hcat @ Wo, g1/g2 ----------------------------
__global__ __launch_bounds__(256) void gemm2_kernel(
    const unsigned short* __restrict__ hcat, const float* __restrict__ Wo,
    const float* __restrict__ ao1, const float* __restrict__ ao2,
    float* __restrict__ Wh2, float* __restrict__ g1, float* __restrict__ g2) {
  int n = blockIdx.x * 4 + (threadIdx.x >> 6);
  int l = threadIdx.x & 63;
  float acc[NCLS] = {};
  for (int k = l; k < HID; k += 64) {
    float hv = bf2f(hcat[n * HID + k]);
    const float* wrow = Wo + k * NCLS;
    #pragma unroll
    for (int c = 0; c < NCLS; ++c) acc[c] += hv * wrow[c];
  }
  #pragma unroll
  for (int c = 0; c < NCLS; ++c)
    #pragma unroll
    for (int off = 32; off > 0; off >>= 1) acc[c] += __shfl_xor(acc[c], off, 64);
  if (l == 0) {
    float s1 = 0.f, s2 = 0.f;
    #pragma unroll
    for (int c = 0; c < NCLS; ++c) {
      Wh2[n * NCLS + c] = acc[c];
      s1 += acc[c] * ao1[c];
      s2 += acc[c] * ao2[c];
    }
    g1[n] = s1; g2[n] = s2;
  }
}

// ---------------- ATT2 + log_softmax ---------------------------------------
__global__ __launch_bounds__(256) void att2_kernel(
    const int* __restrict__ adj, const float* __restrict__ g1,
    const float* __restrict__ g2, const float* __restrict__ Wh2,
    float* __restrict__ out) {
  int n = blockIdx.x * 4 + (threadIdx.x >> 6);
  int l = threadIdx.x & 63;
  float g1v = g1[n];
  float M = NEGINF, S = 0.f;
  float acc[NCLS] = {};
  for (int tb = 0; tb < N_NODES; tb += 64) {
    int m = tb + l;
    int a = adj[n * N_NODES + m];
    float v = g1v + g2[m];
    float lv = v > 0.f ? v : GAT_ALPHA * v;
    float logit = a ? lv : NEGINF;
    float tmax = logit;
    #pragma unroll
    for (int off = 32; off > 0; off >>= 1) tmax = fmaxf(tmax, __shfl_xor(tmax, off, 64));
    float newM = fmaxf(M, tmax);
    float sc = __expf(M - newM);
    M = newM;
    float p = __expf(logit - newM);
    S = S * sc + p;
    const float* wrow = Wh2 + m * NCLS;
    #pragma unroll
    for (int c = 0; c < NCLS; ++c) acc[c] = acc[c] * sc + p * wrow[c];
  }
  #pragma unroll
  for (int off = 32; off > 0; off >>= 1) S += __shfl_xor(S, off, 64);
  #pragma unroll
  for (int c = 0; c < NCLS; ++c)
    #pragma unroll
    for (int off = 32; off > 0; off >>= 1) acc[c] += __shfl_xor(acc[c], off, 64);
  float rS = 1.0f / S;
  float lo[NCLS]; float mx = -1e30f;
  #pragma unroll
  for (int c = 0; c < NCLS; ++c) { lo[c] = acc[c] * rS; mx = fmaxf(mx, lo[c]); }
  float se = 0.f;
  #pragma unroll
  for (int c = 0; c < NCLS; ++c) se += __expf(lo[c] - mx);
  float lse = mx + __logf(se);
  if (l == 0) {
    #pragma unroll
    for (int c = 0; c < NCLS; ++c) out[n * NCLS + c] = lo[c] - lse;
  }
}

extern "C" void kernel_launch(void* const* d_in, const int* in_sizes, int n_in,
                              void* d_out, int out_size, void* d_ws, size_t ws_size,
                              hipStream_t stream) {
  (void)in_sizes; (void)n_in; (void)out_size; (void)ws_size;
  const float* x   = (const float*)d_in[0];
  const int*   adj = (const int*)d_in[1];
  const float* W   = (const float*)d_in[2];
  const float* a1  = (const float*)d_in[3];
  const float* a2  = (const float*)d_in[4];
  const float* Wo  = (const float*)d_in[5];
  const float* ao1 = (const float*)d_in[6];
  const float* ao2 = (const float*)d_in[7];
  float* out = (float*)d_out;

  char* ws = (char*)d_ws;
  float* Whcat        = (float*)ws;          ws += (size_t)N_NODES * HID * 4;
  unsigned short* WhbT= (unsigned short*)ws; ws += (size_t)HID * N_NODES * 2;
  float* f1           = (float*)ws;          ws += (size_t)NHEAD * N_NODES * 4;
  float* f2           = (float*)ws;          ws += (size_t)NHEAD * N_NODES * 4;
  unsigned short* hcat= (unsigned short*)ws; ws += (size_t)N_NODES * HID * 2;
  float* Wh2          = (float*)ws;          ws += (size_t)N_NODES * NCLS * 4;
  float* g1           = (float*)ws;          ws += (size_t)N_NODES * 4;
  float* g2           = (float*)ws;          ws += (size_t)N_NODES * 4;

  gemm1_kernel<<<dim3(64, 8), 256, 0, stream>>>(x, W, Whcat, WhbT);
  f12_kernel<<<N_NODES, 512, 0, stream>>>(Whcat, a1, a2, f1, f2);
  att1_kernel<<<N_NODES / 16, 512, 0, stream>>>(adj, f1, f2, WhbT, hcat);
  gemm2_kernel<<<N_NODES / 4, 256, 0, stream>>>(hcat, Wo, ao1, ao2, Wh2, g1, g2);
  att2_kernel<<<N_NODES / 4, 256, 0, stream>>>(adj, g1, g2, Wh2, out);
}